// Round 1
// 116.846 us; speedup vs baseline: 1.0261x; 1.0261x over previous
//
#include <hip/hip_runtime.h>
#include <math.h>

// Problem constants (from reference setup_inputs)
constexpr int B = 16, N = 1024, Cin = 64, C = 64, K = 3;
constexpr int BN = B * N;
constexpr int GRID = 512;          // 32 blocks per batch, 2 blocks/CU co-resident
constexpr int BLOCK = 512;        // 8 waves/block -> 16 waves/CU (was 8)
constexpr int ROWS = 32;          // n-rows per block
#define LN_EPS 1e-5f

// ---------------------------------------------------------------------------
// Per-batch barrier (32 blocks) on a private 128B line. Proven r7-r9.
// ---------------------------------------------------------------------------
__device__ __forceinline__ void bbar(unsigned int* cnt) {
    __syncthreads();
    if (threadIdx.x == 0) {
        __hip_atomic_fetch_add(cnt, 1u, __ATOMIC_RELAXED, __HIP_MEMORY_SCOPE_AGENT);
        int spins = 0;
        while (__hip_atomic_load(cnt, __ATOMIC_RELAXED, __HIP_MEMORY_SCOPE_AGENT) < 32u) {
            __builtin_amdgcn_s_sleep(8);
            if (++spins > (1 << 17)) break;              // bail, no hang
        }
    }
    __syncthreads();
}

// ---------------------------------------------------------------------------
// Persistent kernel, 512 blocks x 512. Block (b = blk/32, rbase = (blk%32)*32)
// owns 32 n-rows of batch b for all three passes. The 128 KB A-tile lives
// ON-CHIP for the whole kernel:
//   rows rbase+ 0..15 -> LDS  As[16][1024]  (64 KB, async global_load_lds)
//   rows rbase+16..31 -> VGPR Ar[2][4] per thread (32 regs, asm-pinned)
// h slice (32 KB) is prefetched into 16 pinned VGPRs during phase 0 and
// scattered to LDS only in phase 4a (removes the serial tail load).
// Load-issue order: X (oldest in vmcnt queue, so P0's reduce waits only on
// them) -> A-LDS (async) -> A-regs -> h. bbar's syncthreads drains vmcnt(0),
// which is the completion wait for the async LDS stores.
//  Phase 0: X loads, A->LDS(async)+regs, h->regs, P0 = X.sum(-1) | bbar
//  Pass 1:  P1 = A @ P0  (LDS half + reg half)                   | bbar
//  Pass 2:  P2 = A @ P1                                          | bbar
//  Pass 3:  P3 (stays in LDS)                                    | syncthreads
//  Phase 4: hl <- pinned regs (LDS scatter), taps + LayerNorm + tanh
// ---------------------------------------------------------------------------
__global__ void __launch_bounds__(BLOCK, 4)   // 4 waves/EU -> 2 blocks/CU
fused_persist(const float* __restrict__ A, const float* __restrict__ X,
              const float* __restrict__ h, const float* __restrict__ gamma,
              const float* __restrict__ beta, float* __restrict__ out,
              unsigned int* __restrict__ bar, float* __restrict__ P) {
    __shared__ __align__(16) union SU {
        float As[16][1024];            // 64 KB: A rows rbase+0..15 (passes 1-3)
        float hl[K + 1][ROWS][65];     // 33 KB: h^T slice (phase 4 only)
    } u;
    __shared__ __align__(16) float4 xs[N / 4];      // 4 KB: current x-vector
    __shared__ float p3s[ROWS];
    const int tid   = threadIdx.x;
    const int lane  = tid & 63;
    const int w     = tid >> 6;                     // wave 0..7
    const int b     = blockIdx.x >> 5;              // batch
    const int rbase = (blockIdx.x & 31) * ROWS;     // this block's rows
    unsigned int* mybar = bar + (size_t)b * 3 * 32; // 3 private lines per batch
    const float* Ab = A + ((size_t)b << 20);

    // ---- Phase 0 (i): X loads FIRST (oldest vmcnt entries) ----------------
    float xv[4];
    {
        const float* Xb = X + ((size_t)b * N + rbase) * Cin;
        #pragma unroll
        for (int j = 0; j < 4; ++j)
            xv[j] = Xb[(size_t)(w * 4 + j) * Cin + lane];   // coalesced 256B
    }

    // ---- Phase 0 (ii): A rows rbase+0..15 -> LDS, async (no VGPR trip) ----
    // Wave-uniform LDS base + lane*16 is exactly our linear As layout: a
    // wave's 64 lanes cover 64 consecutive float4 slots within one row.
    #pragma unroll
    for (int i = 0; i < 8; ++i) {
        const int wavebase = i * 512 + w * 64;      // float4 slot, wave-uniform
        const int row      = wavebase >> 8;         // 0..15
        const int col4     = (wavebase & 255) + lane;
        const float* gsrc  = Ab + (size_t)(rbase + row) * N + (size_t)col4 * 4;
        float* ldst = (float*)(((float4*)&u.As[0][0]) + wavebase);
        __builtin_amdgcn_global_load_lds(
            (const __attribute__((address_space(1))) void*)gsrc,
            (__attribute__((address_space(3))) void*)ldst, 16, 0, 0);
    }

    // ---- Phase 0 (iii): A rows rbase+16..31 -> registers ------------------
    float4 Ar[2][4];
    #pragma unroll
    for (int j = 0; j < 2; ++j) {
        const float4* rp = (const float4*)(Ab + (size_t)(rbase + 16 + w * 2 + j) * N);
        #pragma unroll
        for (int k = 0; k < 4; ++k)
            Ar[j][k] = rp[k * 64 + lane];           // coalesced 1 KB/instr
    }

    // ---- Phase 0 (iv): h slice -> registers (overlaps the A load) ---------
    // thread -> (i4 = tid>>7, cofs = (tid&127)>>3, nngrp = tid&7)
    const int i4    = tid >> 7;                     // 0..3 (tap index)
    const int cofs  = (tid & 127) >> 3;             // 0..15
    const int nngrp = tid & 7;                      // 0..7
    float4 hv[4];
    #pragma unroll
    for (int c0 = 0; c0 < 4; ++c0) {
        const int c = c0 * 16 + cofs;
        hv[c0] = *(const float4*)(h + ((size_t)i4 * C + c) * N + rbase + nngrp * 4);
    }

    // ---- Phase 0 (v): P0 reduce -- waits only on xv (issued first) --------
    {
        float* P0 = P + (size_t)b * N;
        #pragma unroll
        for (int j = 0; j < 4; ++j) {
            float v = xv[j];
            #pragma unroll
            for (int off = 32; off; off >>= 1) v += __shfl_xor(v, off);
            if (lane == 0)
                __hip_atomic_store(&P0[rbase + w * 4 + j], v, __ATOMIC_RELAXED,
                                   __HIP_MEMORY_SCOPE_AGENT);
        }
    }

    // Pin: asm-defined values cannot be rematerialized -> loads stay hoisted
    // (rounds 8/9: plain register arrays got re-loaded 3x).
    #pragma unroll
    for (int j = 0; j < 2; ++j)
        #pragma unroll
        for (int k = 0; k < 4; ++k)
            asm volatile("" : "+v"(Ar[j][k].x), "+v"(Ar[j][k].y),
                              "+v"(Ar[j][k].z), "+v"(Ar[j][k].w));
    #pragma unroll
    for (int c0 = 0; c0 < 4; ++c0)
        asm volatile("" : "+v"(hv[c0].x), "+v"(hv[c0].y),
                          "+v"(hv[c0].z), "+v"(hv[c0].w));

    bbar(mybar);              // P0[b] complete; vmcnt(0) drain -> As valid

    // ---- Passes 1..3: matvec, A entirely on-chip --------------------------
    for (int it = 0; it < 3; ++it) {
        const float* xsrc = P + (size_t)it * BN + (size_t)b * N;
        if (tid < 256) xs[tid] = ((const float4*)xsrc)[tid];  // fresh after bbar
        __syncthreads();

        float accL[2] = {0.f, 0.f};                // LDS rows  rbase + w*2 + j
        float accR[2] = {0.f, 0.f};                // reg rows  rbase + 16 + w*2 + j
        #pragma unroll
        for (int k = 0; k < 4; ++k) {
            float4 xx = xs[k * 64 + lane];
            #pragma unroll
            for (int j = 0; j < 2; ++j) {
                float4 aL = ((const float4*)u.As[w * 2 + j])[k * 64 + lane];
                accL[j] += aL.x * xx.x + aL.y * xx.y + aL.z * xx.z + aL.w * xx.w;
                float4 aR = Ar[j][k];
                accR[j] += aR.x * xx.x + aR.y * xx.y + aR.z * xx.z + aR.w * xx.w;
            }
        }
        #pragma unroll
        for (int off = 32; off; off >>= 1)
            #pragma unroll
            for (int j = 0; j < 2; ++j) {
                accL[j] += __shfl_xor(accL[j], off);
                accR[j] += __shfl_xor(accR[j], off);
            }

        if (lane == 0) {
            if (it < 2) {
                float* ydst = P + (size_t)(it + 1) * BN + (size_t)b * N + rbase;
                #pragma unroll
                for (int j = 0; j < 2; ++j) {
                    __hip_atomic_store(&ydst[w * 2 + j],      accL[j],
                                       __ATOMIC_RELAXED, __HIP_MEMORY_SCOPE_AGENT);
                    __hip_atomic_store(&ydst[16 + w * 2 + j], accR[j],
                                       __ATOMIC_RELAXED, __HIP_MEMORY_SCOPE_AGENT);
                }
            } else {                                // P3 stays in LDS
                #pragma unroll
                for (int j = 0; j < 2; ++j) {
                    p3s[w * 2 + j]      = accL[j];
                    p3s[16 + w * 2 + j] = accR[j];
                }
            }
        }
        if (it < 2) bbar(mybar + (1 + it) * 32);    // publish P[it+1][b]
        else        __syncthreads();                // p3s visible; As now dead
    }

    // ---- Phase 4a: scatter pinned h regs -> hl (LDS only, no global) ------
    #pragma unroll
    for (int c0 = 0; c0 < 4; ++c0) {
        const int c   = c0 * 16 + cofs;
        const int nn0 = nngrp * 4;
        u.hl[i4][nn0 + 0][c] = hv[c0].x;
        u.hl[i4][nn0 + 1][c] = hv[c0].y;
        u.hl[i4][nn0 + 2][c] = hv[c0].z;
        u.hl[i4][nn0 + 3][c] = hv[c0].w;
    }
    __syncthreads();

    // ---- Phase 4b: taps + LayerNorm + tanh (wave w: 4 n's, lane = c) ------
    const float g  = gamma[lane];
    const float be = beta[lane];
    #pragma unroll
    for (int j = 0; j < 4; ++j) {
        const int nn = w * 4 + j;
        const int n  = rbase + nn;
        float y = p3s[nn] * u.hl[3][nn][lane];
        #pragma unroll
        for (int i = 0; i < 3; ++i) {
            float pv = P[(size_t)i * BN + (size_t)b * N + n];   // wave-uniform, cached
            y += pv * u.hl[i][nn][lane];
        }
        float s = y;
        #pragma unroll
        for (int off = 32; off; off >>= 1) s += __shfl_xor(s, off);
        float mu = s * (1.0f / 64.0f);
        float d  = y - mu;
        float v  = d * d;
        #pragma unroll
        for (int off = 32; off; off >>= 1) v += __shfl_xor(v, off);
        float var = v * (1.0f / 64.0f);
        float yn  = d * rsqrtf(var + LN_EPS) * g + be;
        out[((size_t)b * N + n) * C + lane] = tanhf(yn);
    }
}

// ---------------------------------------------------------------------------
extern "C" void kernel_launch(void* const* d_in, const int* in_sizes, int n_in,
                              void* d_out, int out_size, void* d_ws, size_t ws_size,
                              hipStream_t stream) {
    const float* A     = (const float*)d_in[0];  // [B,N,N]
    const float* X     = (const float*)d_in[1];  // [B,N,Cin]
    const float* h     = (const float*)d_in[2];  // [K+1,C,N]
    const float* gamma = (const float*)d_in[3];  // [C]
    const float* beta  = (const float*)d_in[4];  // [C]
    float* out = (float*)d_out;                  // [B,N,C]

    // ws layout: barrier counters (16 batches x 3 x 32 uints = 6 KB, zeroed
    // here; ws arrives 0xAA-poisoned), then P[3][B][N] (192 KB).
    unsigned int* bar = (unsigned int*)d_ws;
    float* P = (float*)((char*)d_ws + 8192);

    hipMemsetAsync(bar, 0, B * 3 * 32 * sizeof(unsigned int), stream);
    fused_persist<<<GRID, BLOCK, 0, stream>>>(A, X, h, gamma, beta, out, bar, P);
}

// Round 3
// 115.554 us; speedup vs baseline: 1.0376x; 1.0112x over previous
//
#include <hip/hip_runtime.h>
#include <math.h>

// Problem constants (from reference setup_inputs)
constexpr int B = 16, N = 1024, Cin = 64, C = 64, K = 3;
constexpr int BN = B * N;
constexpr int GRID = 512;          // 32 blocks per batch, 2 blocks/CU co-resident
constexpr int BLOCK = 512;         // 8 waves/block -> 16 waves/CU
constexpr int ROWS = 32;           // n-rows per block
#define LN_EPS 1e-5f

// ---------------------------------------------------------------------------
// Per-batch barrier (32 blocks) on a private 128B line. Proven r7-r9/r0/r1.
// (R2's init-free slot barrier failed correctness: either poison-sign
// assumption or per-slot store visibility. Reverted to the proven RMW form;
// counters are zeroed by the 6 KB memset in kernel_launch each replay.)
// ---------------------------------------------------------------------------
__device__ __forceinline__ void bbar(unsigned int* cnt) {
    __syncthreads();                       // drains vmcnt(0): P stores + A-LDS
    if (threadIdx.x == 0) {
        __hip_atomic_fetch_add(cnt, 1u, __ATOMIC_RELAXED, __HIP_MEMORY_SCOPE_AGENT);
        int spins = 0;
        while (__hip_atomic_load(cnt, __ATOMIC_RELAXED, __HIP_MEMORY_SCOPE_AGENT) < 32u) {
            __builtin_amdgcn_s_sleep(8);
            if (++spins > (1 << 17)) break;              // bail, no hang
        }
    }
    __syncthreads();
}

// ---------------------------------------------------------------------------
// Persistent kernel, 512 blocks x 512. Block (b = blk/32, rbase = (blk%32)*32)
// owns 32 n-rows of batch b for all three passes. The 128 KB A-tile lives
// ON-CHIP for the whole kernel:
//   rows rbase+ 0..15 -> LDS  As[16][1024]  (64 KB, async global_load_lds)
//   rows rbase+16..31 -> VGPR Ar[2][4] per thread (32 regs, asm-pinned)
// h slice (32 KB) prefetched into 16 pinned VGPRs during phase 0, scattered
// to LDS in phase 4a. All P values this block produces are mirrored into a
// 512 B LDS history ph[4][32], so phase 4b does ZERO global reads.
// Load-issue order: X (oldest vmcnt entries -> P0 reduce waits only on them)
// -> A-LDS (async) -> A-regs -> h. bbar's first syncthreads drains vmcnt(0),
// which is the completion wait for the async LDS stores.
// ---------------------------------------------------------------------------
__global__ void __launch_bounds__(BLOCK, 4)   // 4 waves/EU -> 2 blocks/CU
fused_persist(const float* __restrict__ A, const float* __restrict__ X,
              const float* __restrict__ h, const float* __restrict__ gamma,
              const float* __restrict__ beta, float* __restrict__ out,
              unsigned int* __restrict__ bar, float* __restrict__ P) {
    __shared__ __align__(16) union SU {
        float As[16][1024];            // 64 KB: A rows rbase+0..15 (passes 1-3)
        float hl[K + 1][ROWS][65];     // 33 KB: h^T slice (phase 4 only)
    } u;
    __shared__ __align__(16) float4 xs[N / 4];      // 4 KB: current x-vector
    __shared__ float ph[K + 1][ROWS];  // 512 B: this block's P0..P3 rows
    const int tid   = threadIdx.x;
    const int lane  = tid & 63;
    const int w     = tid >> 6;                     // wave 0..7
    const int b     = blockIdx.x >> 5;              // batch
    const int rbase = (blockIdx.x & 31) * ROWS;     // this block's rows
    unsigned int* mybar = bar + (size_t)b * 3 * 32; // 3 private lines per batch
    const float* Ab = A + ((size_t)b << 20);

    // ---- Phase 0 (i): X loads FIRST (oldest vmcnt entries), vectorized ----
    // 32 rows x 64 ch = 512 float4; thread tid -> float4 slot tid
    // (row = tid>>4, slot-in-row = tid&15).
    const float* Xb = X + ((size_t)b * N + rbase) * Cin;
    float4 xq = ((const float4*)Xb)[tid];

    // ---- Phase 0 (ii): A rows rbase+0..15 -> LDS, async (no VGPR trip) ----
    #pragma unroll
    for (int i = 0; i < 8; ++i) {
        const int wavebase = i * 512 + w * 64;      // float4 slot, wave-uniform
        const int row      = wavebase >> 8;         // 0..15
        const int col4     = (wavebase & 255) + lane;
        const float* gsrc  = Ab + (size_t)(rbase + row) * N + (size_t)col4 * 4;
        float* ldst = (float*)(((float4*)&u.As[0][0]) + wavebase);
        __builtin_amdgcn_global_load_lds(
            (const __attribute__((address_space(1))) void*)gsrc,
            (__attribute__((address_space(3))) void*)ldst, 16, 0, 0);
    }

    // ---- Phase 0 (iii): A rows rbase+16..31 -> registers ------------------
    float4 Ar[2][4];
    #pragma unroll
    for (int j = 0; j < 2; ++j) {
        const float4* rp = (const float4*)(Ab + (size_t)(rbase + 16 + w * 2 + j) * N);
        #pragma unroll
        for (int k = 0; k < 4; ++k)
            Ar[j][k] = rp[k * 64 + lane];           // coalesced 1 KB/instr
    }

    // ---- Phase 0 (iv): h slice -> registers (overlaps the A load) ---------
    const int i4    = tid >> 7;                     // 0..3 (tap index)
    const int cofs  = (tid & 127) >> 3;             // 0..15
    const int nngrp = tid & 7;                      // 0..7
    float4 hv[4];
    #pragma unroll
    for (int c0 = 0; c0 < 4; ++c0) {
        const int c = c0 * 16 + cofs;
        hv[c0] = *(const float4*)(h + ((size_t)i4 * C + c) * N + rbase + nngrp * 4);
    }

    // ---- Phase 0 (v): P0 reduce -- waits only on xq (issued first) --------
    {
        float s = xq.x + xq.y + xq.z + xq.w;        // 4 channels in-register
        #pragma unroll
        for (int off = 8; off; off >>= 1) s += __shfl_xor(s, off);  // 16-group
        if ((lane & 15) == 0) {
            const int row = w * 4 + (lane >> 4);
            __hip_atomic_store(&P[(size_t)b * N + rbase + row], s,
                               __ATOMIC_RELAXED, __HIP_MEMORY_SCOPE_AGENT);
            ph[0][row] = s;
        }
    }

    // Pin: asm-defined values cannot be rematerialized -> loads stay hoisted
    // (rounds 8/9: plain register arrays got re-loaded 3x).
    #pragma unroll
    for (int j = 0; j < 2; ++j)
        #pragma unroll
        for (int k = 0; k < 4; ++k)
            asm volatile("" : "+v"(Ar[j][k].x), "+v"(Ar[j][k].y),
                              "+v"(Ar[j][k].z), "+v"(Ar[j][k].w));
    #pragma unroll
    for (int c0 = 0; c0 < 4; ++c0)
        asm volatile("" : "+v"(hv[c0].x), "+v"(hv[c0].y),
                          "+v"(hv[c0].z), "+v"(hv[c0].w));

    bbar(mybar);              // P0[b] complete; vmcnt(0) drain -> As valid

    // ---- Passes 1..3: matvec, A entirely on-chip --------------------------
    for (int it = 0; it < 3; ++it) {
        const float* xsrc = P + (size_t)it * BN + (size_t)b * N;
        if (tid < 256) xs[tid] = ((const float4*)xsrc)[tid];  // fresh after bbar
        __syncthreads();

        float accL[2] = {0.f, 0.f};                // LDS rows  rbase + w*2 + j
        float accR[2] = {0.f, 0.f};                // reg rows  rbase + 16 + w*2 + j
        #pragma unroll
        for (int k = 0; k < 4; ++k) {
            float4 xx = xs[k * 64 + lane];
            #pragma unroll
            for (int j = 0; j < 2; ++j) {
                float4 aL = ((const float4*)u.As[w * 2 + j])[k * 64 + lane];
                accL[j] += aL.x * xx.x + aL.y * xx.y + aL.z * xx.z + aL.w * xx.w;
                float4 aR = Ar[j][k];
                accR[j] += aR.x * xx.x + aR.y * xx.y + aR.z * xx.z + aR.w * xx.w;
            }
        }
        #pragma unroll
        for (int off = 32; off; off >>= 1)
            #pragma unroll
            for (int j = 0; j < 2; ++j) {
                accL[j] += __shfl_xor(accL[j], off);
                accR[j] += __shfl_xor(accR[j], off);
            }

        if (lane == 0) {
            #pragma unroll
            for (int j = 0; j < 2; ++j) {           // LDS history for phase 4b
                ph[it + 1][w * 2 + j]      = accL[j];
                ph[it + 1][16 + w * 2 + j] = accR[j];
            }
            if (it < 2) {
                float* ydst = P + (size_t)(it + 1) * BN + (size_t)b * N + rbase;
                #pragma unroll
                for (int j = 0; j < 2; ++j) {
                    __hip_atomic_store(&ydst[w * 2 + j],      accL[j],
                                       __ATOMIC_RELAXED, __HIP_MEMORY_SCOPE_AGENT);
                    __hip_atomic_store(&ydst[16 + w * 2 + j], accR[j],
                                       __ATOMIC_RELAXED, __HIP_MEMORY_SCOPE_AGENT);
                }
            }
        }
        if (it < 2) bbar(mybar + (1 + it) * 32);    // publish P[it+1][b]
        else        __syncthreads();                // ph[3] visible; As dead
    }

    // ---- Phase 4a: scatter pinned h regs -> hl (LDS only, no global) ------
    #pragma unroll
    for (int c0 = 0; c0 < 4; ++c0) {
        const int c   = c0 * 16 + cofs;
        const int nn0 = nngrp * 4;
        u.hl[i4][nn0 + 0][c] = hv[c0].x;
        u.hl[i4][nn0 + 1][c] = hv[c0].y;
        u.hl[i4][nn0 + 2][c] = hv[c0].z;
        u.hl[i4][nn0 + 3][c] = hv[c0].w;
    }
    __syncthreads();

    // ---- Phase 4b: taps + LayerNorm + tanh -- fully LDS-local -------------
    const float g  = gamma[lane];
    const float be = beta[lane];
    #pragma unroll
    for (int j = 0; j < 4; ++j) {
        const int nn = w * 4 + j;
        const int n  = rbase + nn;
        float y = ph[0][nn] * u.hl[0][nn][lane]
                + ph[1][nn] * u.hl[1][nn][lane]
                + ph[2][nn] * u.hl[2][nn][lane]
                + ph[3][nn] * u.hl[3][nn][lane];
        float s = y;
        #pragma unroll
        for (int off = 32; off; off >>= 1) s += __shfl_xor(s, off);
        float mu = s * (1.0f / 64.0f);
        float d  = y - mu;
        float v  = d * d;
        #pragma unroll
        for (int off = 32; off; off >>= 1) v += __shfl_xor(v, off);
        float var = v * (1.0f / 64.0f);
        float yn  = d * rsqrtf(var + LN_EPS) * g + be;
        out[((size_t)b * N + n) * C + lane] = tanhf(yn);
    }
}

// ---------------------------------------------------------------------------
extern "C" void kernel_launch(void* const* d_in, const int* in_sizes, int n_in,
                              void* d_out, int out_size, void* d_ws, size_t ws_size,
                              hipStream_t stream) {
    const float* A     = (const float*)d_in[0];  // [B,N,N]
    const float* X     = (const float*)d_in[1];  // [B,N,Cin]
    const float* h     = (const float*)d_in[2];  // [K+1,C,N]
    const float* gamma = (const float*)d_in[3];  // [C]
    const float* beta  = (const float*)d_in[4];  // [C]
    float* out = (float*)d_out;                  // [B,N,C]

    // ws layout: barrier counters (16 batches x 3 x 32 uints = 6 KB, zeroed
    // here; ws arrives poisoned), then P[3][B][N] (192 KB).
    unsigned int* bar = (unsigned int*)d_ws;
    float* P = (float*)((char*)d_ws + 8192);

    hipMemsetAsync(bar, 0, B * 3 * 32 * sizeof(unsigned int), stream);
    fused_persist<<<GRID, BLOCK, 0, stream>>>(A, X, h, gamma, beta, out, bar, P);
}